// Round 5
// baseline (266.231 us; speedup 1.0000x reference)
//
#include <hip/hip_runtime.h>
#include <hip/hip_bf16.h>
#include <stdint.h>

#define B_   8
#define S_   4096
#define SP1_ 4097
#define D_   256
#define R_   512
#define C_   2048
#define BS_  32768          // B*S

typedef __attribute__((ext_vector_type(8))) short bf16x8;
typedef __attribute__((ext_vector_type(4))) float f32x4;
typedef unsigned short u16;

__device__ __forceinline__ u16 f2bf(float f) {
  __hip_bfloat16 h = __float2bfloat16(f);
  return *(u16*)&h;
}
__device__ __forceinline__ float bf2f(u16 u) {
  __hip_bfloat16 h = *(__hip_bfloat16*)&u;
  return __bfloat162float(h);
}

// ================= K1: prep (cast+qsq | w0 | transpose_E | zero | cls copy) =================
#define NCAST 8192
#define W0B   (NCAST)            // 64 blocks
#define TEB   (W0B + 64)         // 1024 blocks
#define ZB    (TEB + 1024)       // 33 blocks
#define CLSB  (ZB + 33)          // 8 blocks
#define K1GRID (CLSB + 8)

__global__ void k_prep(const float* __restrict__ x, const float* __restrict__ clsw,
                       const float* __restrict__ E, u16* __restrict__ posb,
                       float* __restrict__ qsq, float* __restrict__ w0,
                       u16* __restrict__ ET, float* __restrict__ zbase,
                       float* __restrict__ out) {
  __shared__ float sm[33 * 32];
  int blk = blockIdx.x, t = threadIdx.x;
  if (blk < NCAST) {
    // cast pos tokens + per-row q_sq: 4 rows/block, one per wave
    int wv = t >> 6, lane = t & 63;
    int row = blk * 4 + wv;
    int b = row >> 12, s = row & 4095;
    const float4 v = *(const float4*)(x + (size_t)b * SP1_ * D_ + (size_t)(s + 1) * D_ + lane * 4);
    ushort4 u;
    u.x = f2bf(v.x); u.y = f2bf(v.y); u.z = f2bf(v.z); u.w = f2bf(v.w);
    *(ushort4*)(posb + (size_t)row * D_ + lane * 4) = u;
    float ss = v.x * v.x + v.y * v.y + v.z * v.z + v.w * v.w;
    #pragma unroll
    for (int off = 1; off < 64; off <<= 1) ss += __shfl_xor(ss, off);
    if (lane == 0) qsq[row] = ss;
  } else if (blk < TEB) {
    // w0[b,r] = sum_d cls[b,d]*clsw[d,r]
    int id = blk - W0B;                       // 0..63 = b*8 + rc
    int b = id >> 3, rc = id & 7;
    int r = rc * 64 + (t & 63);
    int dg = t >> 6;
    const float* cls = x + (size_t)b * SP1_ * D_;
    float a = 0.f;
    for (int d = dg * 64; d < dg * 64 + 64; d++) a += cls[d] * clsw[d * R_ + r];
    sm[t] = a;
    __syncthreads();
    if (t < 64) w0[b * R_ + r] = sm[t] + sm[t + 64] + sm[t + 128] + sm[t + 192];
  } else if (blk < ZB) {
    // ET[c,r] = bf16(E[r,c])
    int id = blk - TEB;                       // 0..1023
    int c0 = (id & 63) * 32, r0 = (id >> 6) * 32;
    int tx = t & 31, ty = t >> 5;             // 32 x 8
    float (*tile)[33] = (float(*)[33])sm;
    #pragma unroll
    for (int i = 0; i < 4; i++)
      tile[ty + i * 8][tx] = E[(size_t)(r0 + ty + i * 8) * C_ + c0 + tx];
    __syncthreads();
    #pragma unroll
    for (int i = 0; i < 4; i++)
      ET[(size_t)(c0 + ty + i * 8) * R_ + r0 + tx] = f2bf(tile[tx][ty + i * 8]);
  } else if (blk < CLSB) {
    // zero esq/hist/acc region: 131328 B = 32832 u32
    int id = blk - ZB;
    int o1 = id * 1024 + t;       if (o1 < 32832) ((uint32_t*)zbase)[o1] = 0u;
    int o2 = id * 1024 + 256 + t; if (o2 < 32832) ((uint32_t*)zbase)[o2] = 0u;
    int o3 = id * 1024 + 512 + t; if (o3 < 32832) ((uint32_t*)zbase)[o3] = 0u;
    int o4 = id * 1024 + 768 + t; if (o4 < 32832) ((uint32_t*)zbase)[o4] = 0u;
  } else {
    // cls token passthrough: 1 block per b
    int b = blk - CLSB;
    size_t xb = (size_t)b * SP1_ * D_;
    if (t < 64) *(float4*)(out + xb + t * 4) = *(const float4*)(x + xb + t * 4);
  }
}

// ================= K2: softmax -> proj bf16 =================
__global__ void k_softmax(const float* __restrict__ x, const float* __restrict__ w0,
                          const float* __restrict__ clsb, u16* __restrict__ proj) {
  int bd = blockIdx.x;
  int b = bd >> 8, d = bd & 255;
  float c = x[(size_t)b * SP1_ * D_ + d];
  int t = threadIdx.x;
  float l0 = c * w0[b * R_ + t] + clsb[t];
  float l1 = c * w0[b * R_ + t + 256] + clsb[t + 256];
  __shared__ float red[256];
  red[t] = fmaxf(l0, l1);
  __syncthreads();
  for (int st = 128; st; st >>= 1) { if (t < st) red[t] = fmaxf(red[t], red[t + st]); __syncthreads(); }
  float m = red[0];
  __syncthreads();
  float e0 = expf(l0 - m), e1 = expf(l1 - m);
  red[t] = e0 + e1;
  __syncthreads();
  for (int st = 128; st; st >>= 1) { if (t < st) red[t] += red[t + st]; __syncthreads(); }
  float inv = 1.0f / red[0];
  size_t base = ((size_t)b * D_ + d) * R_;
  proj[base + t]       = f2bf(e0 * inv);
  proj[base + t + 256] = f2bf(e1 * inv);
}

// ================= K3: emb GEMM, barrier-free register streaming =================
// M=D=256 (proj rows), N=C=2048 (ET rows), K=R=512. Block 128x128, 2x2 waves of 64x64.
// grid (nt=16, mt=2, b=8) = 256 blocks.
__global__ __launch_bounds__(256) void k_gemm_emb(const u16* __restrict__ proj,
                                                  const u16* __restrict__ ET,
                                                  u16* __restrict__ embT,
                                                  float* __restrict__ esq) {
  int nt = blockIdx.x, mt = blockIdx.y, b = blockIdx.z;
  int n0 = nt * 128, m0 = mt * 128;
  const u16* A  = proj + (size_t)b * D_ * R_;   // d-rows x R
  const u16* Bt = ET;                           // c-rows x R
  int tid = threadIdx.x;
  int wv = tid >> 6, lane = tid & 63, ln = lane & 15, qd = lane >> 4;
  int wr = wv >> 1, wc = wv & 1;
  const u16* Ab = A  + (size_t)(m0 + wr * 64 + ln) * R_ + qd * 8;
  const u16* Bb = Bt + (size_t)(n0 + wc * 64 + ln) * R_ + qd * 8;
  f32x4 acc[4][4];
  #pragma unroll
  for (int mi = 0; mi < 4; mi++)
    #pragma unroll
    for (int ni = 0; ni < 4; ni++) acc[mi][ni] = (f32x4){0.f, 0.f, 0.f, 0.f};

  #pragma unroll
  for (int kf = 0; kf < 16; kf++) {             // K=512 / 32
    bf16x8 af[4], bf[4];
    #pragma unroll
    for (int mi = 0; mi < 4; mi++) af[mi] = *(const bf16x8*)(Ab + (size_t)mi * 16 * R_ + kf * 32);
    #pragma unroll
    for (int ni = 0; ni < 4; ni++) bf[ni] = *(const bf16x8*)(Bb + (size_t)ni * 16 * R_ + kf * 32);
    #pragma unroll
    for (int mi = 0; mi < 4; mi++)
      #pragma unroll
      for (int ni = 0; ni < 4; ni++)
        acc[mi][ni] = __builtin_amdgcn_mfma_f32_16x16x32_bf16(af[mi], bf[ni], acc[mi][ni], 0, 0, 0);
  }
  // epilogue: row = d = m0+wr*64+mi*16+qd*4+reg, col = c = n0+wc*64+ni*16+ln
  #pragma unroll
  for (int ni = 0; ni < 4; ni++) {
    int c = n0 + wc * 64 + ni * 16 + ln;
    float ss = 0.f;
    #pragma unroll
    for (int mi = 0; mi < 4; mi++) {
      int dbase = m0 + wr * 64 + mi * 16 + qd * 4;
      f32x4 v = acc[mi][ni];
      ushort4 u;
      u.x = f2bf(v[0]); u.y = f2bf(v[1]); u.z = f2bf(v[2]); u.w = f2bf(v[3]);
      *(ushort4*)&embT[((size_t)b * C_ + c) * D_ + dbase] = u;
      ss += v[0]*v[0] + v[1]*v[1] + v[2]*v[2] + v[3]*v[3];
    }
    ss += __shfl_xor(ss, 16);
    ss += __shfl_xor(ss, 32);
    if (qd == 0) atomicAdd(&esq[b * C_ + c], ss);
  }
}

// ================= K4: dist GEMM, barrier-free register streaming =================
// M=S=4096 rows (posb), N=C=2048 (embT rows), K=D=256. Block 128x128, 2x2 waves of 64x64.
// grid (ct=16, st=32, b=8) = 4096 blocks. Packed partial argmin writes: pval[ct][b*S+s].
__global__ __launch_bounds__(256) void k_gemm_dist(const u16* __restrict__ posb,
                                                   const u16* __restrict__ embT,
                                                   const float* __restrict__ esq,
                                                   float* __restrict__ pval,
                                                   int* __restrict__ pidx) {
  int ct = blockIdx.x, st = blockIdx.y, b = blockIdx.z;
  int n0 = ct * 128, m0 = st * 128;
  const u16* A  = posb + (size_t)b * S_ * D_;
  const u16* Bt = embT + (size_t)b * C_ * D_;
  int tid = threadIdx.x;
  int wv = tid >> 6, lane = tid & 63, ln = lane & 15, qd = lane >> 4;
  int wr = wv >> 1, wc = wv & 1;
  const u16* Ab = A  + (size_t)(m0 + wr * 64 + ln) * D_ + qd * 8;
  const u16* Bb = Bt + (size_t)(n0 + wc * 64 + ln) * D_ + qd * 8;
  __shared__ float pbv[256];
  __shared__ int   pbi[256];
  f32x4 acc[4][4];
  #pragma unroll
  for (int mi = 0; mi < 4; mi++)
    #pragma unroll
    for (int ni = 0; ni < 4; ni++) acc[mi][ni] = (f32x4){0.f, 0.f, 0.f, 0.f};

  #pragma unroll
  for (int kf = 0; kf < 8; kf++) {              // K=256 / 32
    bf16x8 af[4], bf[4];
    #pragma unroll
    for (int mi = 0; mi < 4; mi++) af[mi] = *(const bf16x8*)(Ab + (size_t)mi * 16 * D_ + kf * 32);
    #pragma unroll
    for (int ni = 0; ni < 4; ni++) bf[ni] = *(const bf16x8*)(Bb + (size_t)ni * 16 * D_ + kf * 32);
    #pragma unroll
    for (int mi = 0; mi < 4; mi++)
      #pragma unroll
      for (int ni = 0; ni < 4; ni++)
        acc[mi][ni] = __builtin_amdgcn_mfma_f32_16x16x32_bf16(af[mi], bf[ni], acc[mi][ni], 0, 0, 0);
  }
  // esq for this wave's 4 col-frags (L2-hot)
  float esqv[4];
  #pragma unroll
  for (int ni = 0; ni < 4; ni++) esqv[ni] = esq[b * C_ + n0 + wc * 64 + ni * 16 + ln];
  // per-row argmin over wave's 64 cols
  #pragma unroll
  for (int mi = 0; mi < 4; mi++) {
    #pragma unroll
    for (int reg = 0; reg < 4; reg++) {
      float bv = 3.4e38f; int bc = 0;
      #pragma unroll
      for (int ni = 0; ni < 4; ni++) {
        int c = wc * 64 + ni * 16 + ln;       // local col in [0,128)
        float sc2 = esqv[ni] - 2.0f * acc[mi][ni][reg];
        if (sc2 < bv || (sc2 == bv && c < bc)) { bv = sc2; bc = c; }
      }
      #pragma unroll
      for (int off = 1; off < 16; off <<= 1) {
        float ov = __shfl_xor(bv, off);
        int   oc = __shfl_xor(bc, off);
        if (ov < bv || (ov == bv && oc < bc)) { bv = ov; bc = oc; }
      }
      if (ln == 0) {
        int rl = mi * 16 + qd * 4 + reg;      // row local to wave's 64 rows
        int slot = (wr * 2 + wc) * 64 + rl;
        pbv[slot] = bv;
        pbi[slot] = bc;
      }
    }
  }
  __syncthreads();
  // combine wc halves, write packed coalesced: pval layout [ct][b*S+s]
  if (tid < 128) {
    int wrr = tid >> 6, rl = tid & 63;
    float v0 = pbv[(wrr * 2 + 0) * 64 + rl]; int i0 = pbi[(wrr * 2 + 0) * 64 + rl];
    float v1 = pbv[(wrr * 2 + 1) * 64 + rl]; int i1 = pbi[(wrr * 2 + 1) * 64 + rl];
    if (v1 < v0 || (v1 == v0 && i1 < i0)) { v0 = v1; i0 = i1; }
    size_t o = (size_t)ct * BS_ + b * S_ + m0 + tid;
    pval[o] = v0;
    pidx[o] = n0 + i0;
  }
}

// ================= K5: reduce partials + hist + SSE + gather + write out =================
__global__ void k_reduce_gather(const float* __restrict__ pval, const int* __restrict__ pidx,
                                const float* __restrict__ qsq, const u16* __restrict__ embT,
                                int* __restrict__ hist, float* __restrict__ acc,
                                float* __restrict__ out) {
  int blk = blockIdx.x;                       // 512 blocks x 64 rows
  int t = threadIdx.x;
  int wv = t >> 6, lane = t & 63;
  int g0 = blk * 64;                          // first global row (b*S+s)
  int b = g0 >> 12;
  __shared__ float vbuf[4][64];
  __shared__ int   ibuf[4][64];
  __shared__ int   fidx[64];
  int g = g0 + lane;
  float bv = 3.4e38f; int bi = 0;
  #pragma unroll
  for (int j = 0; j < 4; j++) {
    int ctn = wv * 4 + j;
    float v = pval[(size_t)ctn * BS_ + g];
    int  ix = pidx[(size_t)ctn * BS_ + g];
    if (v < bv || (v == bv && ix < bi)) { bv = v; bi = ix; }
  }
  vbuf[wv][lane] = bv;
  ibuf[wv][lane] = bi;
  __syncthreads();
  if (t < 64) {
    float fv = vbuf[0][t]; int fi = ibuf[0][t];
    #pragma unroll
    for (int w = 1; w < 4; w++) {
      float v = vbuf[w][t]; int ix = ibuf[w][t];
      if (v < fv || (v == fv && ix < fi)) { fv = v; fi = ix; }
    }
    fidx[t] = fi;
    atomicAdd(&hist[b * C_ + fi], 1);
    float sse = fv + qsq[g0 + t];
    #pragma unroll
    for (int off = 1; off < 64; off <<= 1) sse += __shfl_xor(sse, off);
    if (t == 0) atomicAdd(&acc[0], sse);
  }
  __syncthreads();
  // gather: wave wv writes rows [wv*16, wv*16+16)
  size_t xb = (size_t)b * SP1_ * D_;
  const u16* eb = embT + (size_t)b * C_ * D_;
  #pragma unroll
  for (int j = 0; j < 16; j++) {
    int r = wv * 16 + j;
    int ix = fidx[r];
    int s = (g0 + r) & 4095;
    ushort4 q4 = *(const ushort4*)(eb + (size_t)ix * D_ + lane * 4);
    float4 q;
    q.x = bf2f(q4.x); q.y = bf2f(q4.y); q.z = bf2f(q4.z); q.w = bf2f(q4.w);
    *(float4*)(out + xb + (size_t)(s + 1) * D_ + lane * 4) = q;
  }
}

// ================= K6: perplexity + final scalars =================
__global__ void k_perp(const int* __restrict__ hist, float* __restrict__ acc,
                       float* __restrict__ out) {
  int b = blockIdx.x, t = threadIdx.x;
  float ps = 0.f;
  for (int c = t; c < C_; c += 256) {
    float p = (float)hist[b * C_ + c] * (1.0f / (float)S_);
    ps += p * logf(p + 1e-10f);
  }
  __shared__ float red[256];
  red[t] = ps;
  __syncthreads();
  for (int st = 128; st; st >>= 1) { if (t < st) red[t] += red[t + st]; __syncthreads(); }
  if (t == 0) {
    atomicAdd(&acc[1], expf(-red[0]) * (1.0f / (float)B_));
    __threadfence();
    int done = atomicAdd((int*)acc + 2, 1);
    if (done == B_ - 1) {
      float P = atomicAdd(&acc[1], 0.0f);
      float SSE = atomicAdd(&acc[0], 0.0f);
      float L = SSE * (1.0f / 8388608.0f);
      size_t base = (size_t)B_ * SP1_ * D_;
      out[base + 0] = P;
      out[base + 1] = L;
      out[base + 2] = L;
      out[base + 3] = L + 0.25f * L;
    }
  }
}

// ---------------- workspace layout (bytes); esq/hist/acc contiguous (zeroed by K1) ----------------
#define OFF_W0    0u
#define OFF_ESQ   16384u
#define OFF_HIST  (OFF_ESQ + 65536u)
#define OFF_ACC   (OFF_HIST + 65536u)
#define OFF_PROJ  (OFF_ACC + 256u)
#define OFF_ET    (OFF_PROJ + 2097152u)
#define OFF_EMBT  (OFF_ET + 2097152u)
#define OFF_POSB  (OFF_EMBT + 8388608u)
#define OFF_PVAL  (OFF_POSB + 16777216u)
#define OFF_PIDX  (OFF_PVAL + 2097152u)
#define OFF_QSQ   (OFF_PIDX + 2097152u)

extern "C" void kernel_launch(void* const* d_in, const int* in_sizes, int n_in,
                              void* d_out, int out_size, void* d_ws, size_t ws_size,
                              hipStream_t stream) {
  (void)in_sizes; (void)n_in; (void)out_size; (void)ws_size;
  const float* x    = (const float*)d_in[0];
  const float* E    = (const float*)d_in[1];
  const float* clsw = (const float*)d_in[2];
  const float* clsb = (const float*)d_in[3];
  float* out = (float*)d_out;

  char* ws = (char*)d_ws;
  float* w0   = (float*)(ws + OFF_W0);
  float* esq  = (float*)(ws + OFF_ESQ);
  int*   hist = (int*)  (ws + OFF_HIST);
  float* acc  = (float*)(ws + OFF_ACC);
  u16*   proj = (u16*)  (ws + OFF_PROJ);
  u16*   ET   = (u16*)  (ws + OFF_ET);
  u16*   embT = (u16*)  (ws + OFF_EMBT);
  u16*   posb = (u16*)  (ws + OFF_POSB);
  float* pval = (float*)(ws + OFF_PVAL);
  int*   pidx = (int*)  (ws + OFF_PIDX);
  float* qsq  = (float*)(ws + OFF_QSQ);

  k_prep<<<K1GRID, 256, 0, stream>>>(x, clsw, E, posb, qsq, w0, ET, esq, out);
  k_softmax<<<B_ * D_, 256, 0, stream>>>(x, w0, clsb, proj);
  k_gemm_emb<<<dim3(16, 2, B_), 256, 0, stream>>>(proj, ET, embT, esq);
  k_gemm_dist<<<dim3(16, 32, B_), 256, 0, stream>>>(posb, embT, esq, pval, pidx);
  k_reduce_gather<<<512, 256, 0, stream>>>(pval, pidx, qsq, embT, hist, acc, out);
  k_perp<<<B_, 256, 0, stream>>>(hist, acc, out);
}

// Round 6
// 201.787 us; speedup vs baseline: 1.3194x; 1.3194x over previous
//
#include <hip/hip_runtime.h>
#include <hip/hip_bf16.h>
#include <stdint.h>

#define B_   8
#define S_   4096
#define SP1_ 4097
#define D_   256
#define R_   512
#define C_   2048
#define BS_  32768          // B*S

typedef __attribute__((ext_vector_type(8))) short bf16x8;
typedef __attribute__((ext_vector_type(4))) float f32x4;
typedef unsigned short u16;

__device__ __forceinline__ u16 f2bf(float f) {
  __hip_bfloat16 h = __float2bfloat16(f);
  return *(u16*)&h;
}
__device__ __forceinline__ float bf2f(u16 u) {
  __hip_bfloat16 h = *(__hip_bfloat16*)&u;
  return __bfloat162float(h);
}

// async global->LDS, 16B per lane; LDS dst = wave-uniform base + lane*16
__device__ __forceinline__ void gload16(const u16* g, u16* l) {
  __builtin_amdgcn_global_load_lds(
      (const __attribute__((address_space(1))) uint32_t*)g,
      (__attribute__((address_space(3))) uint32_t*)l, 16, 0, 0);
}

// ================= K1: prep (cast+qsq | w0 | transpose_E | zero | cls copy) =================
#define NCAST 8192
#define W0B   (NCAST)            // 64 blocks
#define TEB   (W0B + 64)         // 1024 blocks
#define ZB    (TEB + 1024)       // 33 blocks
#define CLSB  (ZB + 33)          // 8 blocks
#define K1GRID (CLSB + 8)

__global__ void k_prep(const float* __restrict__ x, const float* __restrict__ clsw,
                       const float* __restrict__ E, u16* __restrict__ posb,
                       float* __restrict__ qsq, float* __restrict__ w0,
                       u16* __restrict__ ET, float* __restrict__ zbase,
                       float* __restrict__ out) {
  __shared__ float sm[33 * 32];
  int blk = blockIdx.x, t = threadIdx.x;
  if (blk < NCAST) {
    int wv = t >> 6, lane = t & 63;
    int row = blk * 4 + wv;
    int b = row >> 12, s = row & 4095;
    const float4 v = *(const float4*)(x + (size_t)b * SP1_ * D_ + (size_t)(s + 1) * D_ + lane * 4);
    ushort4 u;
    u.x = f2bf(v.x); u.y = f2bf(v.y); u.z = f2bf(v.z); u.w = f2bf(v.w);
    *(ushort4*)(posb + (size_t)row * D_ + lane * 4) = u;
    float ss = v.x * v.x + v.y * v.y + v.z * v.z + v.w * v.w;
    #pragma unroll
    for (int off = 1; off < 64; off <<= 1) ss += __shfl_xor(ss, off);
    if (lane == 0) qsq[row] = ss;
  } else if (blk < TEB) {
    int id = blk - W0B;                       // 0..63 = b*8 + rc
    int b = id >> 3, rc = id & 7;
    int r = rc * 64 + (t & 63);
    int dg = t >> 6;
    const float* cls = x + (size_t)b * SP1_ * D_;
    float a = 0.f;
    for (int d = dg * 64; d < dg * 64 + 64; d++) a += cls[d] * clsw[d * R_ + r];
    sm[t] = a;
    __syncthreads();
    if (t < 64) w0[b * R_ + r] = sm[t] + sm[t + 64] + sm[t + 128] + sm[t + 192];
  } else if (blk < ZB) {
    int id = blk - TEB;                       // 0..1023
    int c0 = (id & 63) * 32, r0 = (id >> 6) * 32;
    int tx = t & 31, ty = t >> 5;             // 32 x 8
    float (*tile)[33] = (float(*)[33])sm;
    #pragma unroll
    for (int i = 0; i < 4; i++)
      tile[ty + i * 8][tx] = E[(size_t)(r0 + ty + i * 8) * C_ + c0 + tx];
    __syncthreads();
    #pragma unroll
    for (int i = 0; i < 4; i++)
      ET[(size_t)(c0 + ty + i * 8) * R_ + r0 + tx] = f2bf(tile[tx][ty + i * 8]);
  } else if (blk < CLSB) {
    int id = blk - ZB;
    int o1 = id * 1024 + t;       if (o1 < 32832) ((uint32_t*)zbase)[o1] = 0u;
    int o2 = id * 1024 + 256 + t; if (o2 < 32832) ((uint32_t*)zbase)[o2] = 0u;
    int o3 = id * 1024 + 512 + t; if (o3 < 32832) ((uint32_t*)zbase)[o3] = 0u;
    int o4 = id * 1024 + 768 + t; if (o4 < 32832) ((uint32_t*)zbase)[o4] = 0u;
  } else {
    int b = blk - CLSB;
    size_t xb = (size_t)b * SP1_ * D_;
    if (t < 64) *(float4*)(out + xb + t * 4) = *(const float4*)(x + xb + t * 4);
  }
}

// ================= K2: softmax -> proj bf16 =================
__global__ void k_softmax(const float* __restrict__ x, const float* __restrict__ w0,
                          const float* __restrict__ clsb, u16* __restrict__ proj) {
  int bd = blockIdx.x;
  int b = bd >> 8, d = bd & 255;
  float c = x[(size_t)b * SP1_ * D_ + d];
  int t = threadIdx.x;
  float l0 = c * w0[b * R_ + t] + clsb[t];
  float l1 = c * w0[b * R_ + t + 256] + clsb[t + 256];
  __shared__ float red[256];
  red[t] = fmaxf(l0, l1);
  __syncthreads();
  for (int st = 128; st; st >>= 1) { if (t < st) red[t] = fmaxf(red[t], red[t + st]); __syncthreads(); }
  float m = red[0];
  __syncthreads();
  float e0 = expf(l0 - m), e1 = expf(l1 - m);
  red[t] = e0 + e1;
  __syncthreads();
  for (int st = 128; st; st >>= 1) { if (t < st) red[t] += red[t + st]; __syncthreads(); }
  float inv = 1.0f / red[0];
  size_t base = ((size_t)b * D_ + d) * R_;
  proj[base + t]       = f2bf(e0 * inv);
  proj[base + t + 256] = f2bf(e1 * inv);
}

// ================= K3: emb GEMM, LDS+DMA, 64x128 tile, BK=64, 128B rows (conflict-free) =================
// M=D rows (proj), N=C rows (ET), K=R=512. grid (16 nt, 4 mt, 8 b) = 512 blocks.
// LDS rows 64 u16 = 128 B; slot s of row r holds global chunk s^(r&7) (XOR swizzle, 2-way free).
__global__ __launch_bounds__(256) void k_gemm_emb(const u16* __restrict__ proj,
                                                  const u16* __restrict__ ET,
                                                  u16* __restrict__ embT,
                                                  float* __restrict__ esq) {
  int nt = blockIdx.x, mt = blockIdx.y, b = blockIdx.z;
  int n0 = nt * 128, m0 = mt * 64;
  const u16* A  = proj + (size_t)b * D_ * R_;   // d-rows x R
  const u16* Bt = ET;                           // c-rows x R
  __shared__ u16 tA[64 * 64], tB[128 * 64];     // 8 KB + 16 KB
  int tid = threadIdx.x;
  int wv = tid >> 6, lane = tid & 63, ln = lane & 15, qd = lane >> 4;
  int srow8 = lane >> 3, sc = lane & 7;
  int gc = sc ^ srow8;                          // fetch chunk so slot sc holds chunk sc^(row&7)
  f32x4 acc[8];
  #pragma unroll
  for (int nf = 0; nf < 8; nf++) acc[nf] = (f32x4){0.f, 0.f, 0.f, 0.f};

  for (int kk = 0; kk < R_; kk += 64) {
    __syncthreads();
    #pragma unroll
    for (int i = 0; i < 2; i++) {               // A: 64 rows, 8-row groups, 2 per wave
      int r0 = wv * 16 + i * 8;
      gload16(A + (size_t)(m0 + r0 + srow8) * R_ + kk + gc * 8, &tA[r0 * 64]);
    }
    #pragma unroll
    for (int i = 0; i < 4; i++) {               // B: 128 rows, 4 groups per wave
      int r0 = wv * 32 + i * 8;
      gload16(Bt + (size_t)(n0 + r0 + srow8) * R_ + kk + gc * 8, &tB[r0 * 64]);
    }
    __syncthreads();
    #pragma unroll
    for (int kc = 0; kc < 2; kc++) {
      int slot = (kc * 4 + qd) ^ (ln & 7);
      bf16x8 af = *(bf16x8*)&tA[(wv * 16 + ln) * 64 + slot * 8];
      bf16x8 bfr[8];
      #pragma unroll
      for (int nf = 0; nf < 8; nf++) bfr[nf] = *(bf16x8*)&tB[(nf * 16 + ln) * 64 + slot * 8];
      #pragma unroll
      for (int nf = 0; nf < 8; nf++)
        acc[nf] = __builtin_amdgcn_mfma_f32_16x16x32_bf16(af, bfr[nf], acc[nf], 0, 0, 0);
    }
  }
  // epilogue: row d = m0+wv*16+qd*4+reg, col c = n0+nf*16+ln
  #pragma unroll
  for (int nf = 0; nf < 8; nf++) {
    int c = n0 + nf * 16 + ln;
    int dbase = m0 + wv * 16 + qd * 4;
    f32x4 v = acc[nf];
    ushort4 u;
    u.x = f2bf(v[0]); u.y = f2bf(v[1]); u.z = f2bf(v[2]); u.w = f2bf(v[3]);
    *(ushort4*)&embT[((size_t)b * C_ + c) * D_ + dbase] = u;
    float ss = v[0]*v[0] + v[1]*v[1] + v[2]*v[2] + v[3]*v[3];
    ss += __shfl_xor(ss, 16);
    ss += __shfl_xor(ss, 32);
    if (qd == 0) atomicAdd(&esq[b * C_ + c], ss);
  }
}

// ================= K4: dist GEMM 128x128, BK=32 (round-3 best) + packed partial writes =================
__global__ __launch_bounds__(256) void k_gemm_dist(const u16* __restrict__ posb,
                                                   const u16* __restrict__ embT,
                                                   const float* __restrict__ esq,
                                                   float* __restrict__ pval,
                                                   int* __restrict__ pidx) {
  int ct = blockIdx.x, st = blockIdx.y, b = blockIdx.z;
  int n0 = ct * 128, m0 = st * 128;
  const u16* A  = posb + (size_t)b * S_ * D_;   // S x D
  const u16* Bt = embT + (size_t)b * C_ * D_;   // C x D
  __shared__ u16 tA[4096], tB[4096];
  __shared__ float sh_esq[128];
  __shared__ float pbv[128];
  __shared__ int   pbi[128];
  int tid = threadIdx.x;
  if (tid < 128) sh_esq[tid] = esq[b * C_ + n0 + tid];
  int wv = tid >> 6, lane = tid & 63, ln = lane & 15, qd = lane >> 4;
  int srow = lane >> 2;
  int scol = (((lane & 3) ^ (srow & 3) ^ ((srow >> 2) & 3))) * 8;
  const u16* gA0 = A  + (size_t)(m0 + wv * 16 + srow) * D_ + scol;
  const u16* gA1 = gA0 + (size_t)64 * D_;
  const u16* gB0 = Bt + (size_t)(n0 + wv * 16 + srow) * D_ + scol;
  const u16* gB1 = gB0 + (size_t)64 * D_;
  u16* lA0 = &tA[(wv * 16) * 32];
  u16* lA1 = &tA[(64 + wv * 16) * 32];
  u16* lB0 = &tB[(wv * 16) * 32];
  u16* lB1 = &tB[(64 + wv * 16) * 32];
  int cs8 = ((qd ^ (ln & 3) ^ ((ln >> 2) & 3))) * 8;
  f32x4 acc[2][8];
  #pragma unroll
  for (int mf = 0; mf < 2; mf++)
    #pragma unroll
    for (int nf = 0; nf < 8; nf++) acc[mf][nf] = (f32x4){0.f, 0.f, 0.f, 0.f};

  for (int kk = 0; kk < D_; kk += 32) {
    __syncthreads();
    gload16(gA0 + kk, lA0);
    gload16(gA1 + kk, lA1);
    gload16(gB0 + kk, lB0);
    gload16(gB1 + kk, lB1);
    __syncthreads();
    bf16x8 af[2], bfr[8];
    #pragma unroll
    for (int mf = 0; mf < 2; mf++) af[mf] = *(bf16x8*)&tA[(wv * 32 + mf * 16 + ln) * 32 + cs8];
    #pragma unroll
    for (int nf = 0; nf < 8; nf++) bfr[nf] = *(bf16x8*)&tB[(nf * 16 + ln) * 32 + cs8];
    #pragma unroll
    for (int mf = 0; mf < 2; mf++)
      #pragma unroll
      for (int nf = 0; nf < 8; nf++)
        acc[mf][nf] = __builtin_amdgcn_mfma_f32_16x16x32_bf16(af[mf], bfr[nf], acc[mf][nf], 0, 0, 0);
  }
  // per-row argmin over all 128 cols (each wave owns rows wv*32..wv*32+32)
  #pragma unroll
  for (int mf = 0; mf < 2; mf++) {
    #pragma unroll
    for (int reg = 0; reg < 4; reg++) {
      float bv = 3.4e38f; int bc = 0;
      #pragma unroll
      for (int nf = 0; nf < 8; nf++) {
        int c = nf * 16 + ln;
        float sc2 = sh_esq[c] - 2.0f * acc[mf][nf][reg];
        if (sc2 < bv || (sc2 == bv && c < bc)) { bv = sc2; bc = c; }
      }
      #pragma unroll
      for (int off = 1; off < 16; off <<= 1) {
        float ov = __shfl_xor(bv, off);
        int   oc = __shfl_xor(bc, off);
        if (ov < bv || (ov == bv && oc < bc)) { bv = ov; bc = oc; }
      }
      if (ln == 0) {
        int rl = wv * 32 + mf * 16 + qd * 4 + reg;  // 0..127
        pbv[rl] = bv;
        pbi[rl] = n0 + bc;
      }
    }
  }
  __syncthreads();
  // packed coalesced write: pval layout [ct][b*S+s]
  if (tid < 128) {
    size_t o = (size_t)ct * BS_ + b * S_ + m0 + tid;
    pval[o] = pbv[tid];
    pidx[o] = pbi[tid];
  }
}

// ================= K5: reduce partials + hist + SSE + gather + write out =================
__global__ void k_reduce_gather(const float* __restrict__ pval, const int* __restrict__ pidx,
                                const float* __restrict__ qsq, const u16* __restrict__ embT,
                                int* __restrict__ hist, float* __restrict__ acc,
                                float* __restrict__ out) {
  int blk = blockIdx.x;                       // 512 blocks x 64 rows
  int t = threadIdx.x;
  int wv = t >> 6, lane = t & 63;
  int g0 = blk * 64;                          // first global row (b*S+s)
  int b = g0 >> 12;
  __shared__ float vbuf[4][64];
  __shared__ int   ibuf[4][64];
  __shared__ int   fidx[64];
  int g = g0 + lane;
  float bv = 3.4e38f; int bi = 0;
  #pragma unroll
  for (int j = 0; j < 4; j++) {
    int ctn = wv * 4 + j;
    float v = pval[(size_t)ctn * BS_ + g];
    int  ix = pidx[(size_t)ctn * BS_ + g];
    if (v < bv || (v == bv && ix < bi)) { bv = v; bi = ix; }
  }
  vbuf[wv][lane] = bv;
  ibuf[wv][lane] = bi;
  __syncthreads();
  if (t < 64) {
    float fv = vbuf[0][t]; int fi = ibuf[0][t];
    #pragma unroll
    for (int w = 1; w < 4; w++) {
      float v = vbuf[w][t]; int ix = ibuf[w][t];
      if (v < fv || (v == fv && ix < fi)) { fv = v; fi = ix; }
    }
    fidx[t] = fi;
    atomicAdd(&hist[b * C_ + fi], 1);
    float sse = fv + qsq[g0 + t];
    #pragma unroll
    for (int off = 1; off < 64; off <<= 1) sse += __shfl_xor(sse, off);
    if (t == 0) atomicAdd(&acc[0], sse);
  }
  __syncthreads();
  size_t xb = (size_t)b * SP1_ * D_;
  const u16* eb = embT + (size_t)b * C_ * D_;
  #pragma unroll
  for (int j = 0; j < 16; j++) {
    int r = wv * 16 + j;
    int ix = fidx[r];
    int s = (g0 + r) & 4095;
    ushort4 q4 = *(const ushort4*)(eb + (size_t)ix * D_ + lane * 4);
    float4 q;
    q.x = bf2f(q4.x); q.y = bf2f(q4.y); q.z = bf2f(q4.z); q.w = bf2f(q4.w);
    *(float4*)(out + xb + (size_t)(s + 1) * D_ + lane * 4) = q;
  }
}

// ================= K6: perplexity + final scalars =================
__global__ void k_perp(const int* __restrict__ hist, float* __restrict__ acc,
                       float* __restrict__ out) {
  int b = blockIdx.x, t = threadIdx.x;
  float ps = 0.f;
  for (int c = t; c < C_; c += 256) {
    float p = (float)hist[b * C_ + c] * (1.0f / (float)S_);
    ps += p * logf(p + 1e-10f);
  }
  __shared__ float red[256];
  red[t] = ps;
  __syncthreads();
  for (int st = 128; st; st >>= 1) { if (t < st) red[t] += red[t + st]; __syncthreads(); }
  if (t == 0) {
    atomicAdd(&acc[1], expf(-red[0]) * (1.0f / (float)B_));
    __threadfence();
    int done = atomicAdd((int*)acc + 2, 1);
    if (done == B_ - 1) {
      float P = atomicAdd(&acc[1], 0.0f);
      float SSE = atomicAdd(&acc[0], 0.0f);
      float L = SSE * (1.0f / 8388608.0f);
      size_t base = (size_t)B_ * SP1_ * D_;
      out[base + 0] = P;
      out[base + 1] = L;
      out[base + 2] = L;
      out[base + 3] = L + 0.25f * L;
    }
  }
}

// ---------------- workspace layout (bytes); esq/hist/acc contiguous (zeroed by K1) ----------------
#define OFF_W0    0u
#define OFF_ESQ   16384u
#define OFF_HIST  (OFF_ESQ + 65536u)
#define OFF_ACC   (OFF_HIST + 65536u)
#define OFF_PROJ  (OFF_ACC + 256u)
#define OFF_ET    (OFF_PROJ + 2097152u)
#define OFF_EMBT  (OFF_ET + 2097152u)
#define OFF_POSB  (OFF_EMBT + 8388608u)
#define OFF_PVAL  (OFF_POSB + 16777216u)
#define OFF_PIDX  (OFF_PVAL + 2097152u)
#define OFF_QSQ   (OFF_PIDX + 2097152u)

extern "C" void kernel_launch(void* const* d_in, const int* in_sizes, int n_in,
                              void* d_out, int out_size, void* d_ws, size_t ws_size,
                              hipStream_t stream) {
  (void)in_sizes; (void)n_in; (void)out_size; (void)ws_size;
  const float* x    = (const float*)d_in[0];
  const float* E    = (const float*)d_in[1];
  const float* clsw = (const float*)d_in[2];
  const float* clsb = (const float*)d_in[3];
  float* out = (float*)d_out;

  char* ws = (char*)d_ws;
  float* w0   = (float*)(ws + OFF_W0);
  float* esq  = (float*)(ws + OFF_ESQ);
  int*   hist = (int*)  (ws + OFF_HIST);
  float* acc  = (float*)(ws + OFF_ACC);
  u16*   proj = (u16*)  (ws + OFF_PROJ);
  u16*   ET   = (u16*)  (ws + OFF_ET);
  u16*   embT = (u16*)  (ws + OFF_EMBT);
  u16*   posb = (u16*)  (ws + OFF_POSB);
  float* pval = (float*)(ws + OFF_PVAL);
  int*   pidx = (int*)  (ws + OFF_PIDX);
  float* qsq  = (float*)(ws + OFF_QSQ);

  k_prep<<<K1GRID, 256, 0, stream>>>(x, clsw, E, posb, qsq, w0, ET, esq, out);
  k_softmax<<<B_ * D_, 256, 0, stream>>>(x, w0, clsb, proj);
  k_gemm_emb<<<dim3(16, 4, B_), 256, 0, stream>>>(proj, ET, embT, esq);
  k_gemm_dist<<<dim3(16, 32, B_), 256, 0, stream>>>(posb, embT, esq, pval, pidx);
  k_reduce_gather<<<512, 256, 0, stream>>>(pval, pidx, qsq, embT, hist, acc, out);
  k_perp<<<B_, 256, 0, stream>>>(hist, acc, out);
}